// Round 21
// baseline (150.465 us; speedup 1.0000x reference)
//
#include <hip/hip_runtime.h>
#include <math.h>

#define Hdim 4096
#define NE 256
#define BM 64
#define BK 32
#define NKC (Hdim / BK)          // 128 K-chunks = 16 octos
#define PLANE_ELEMS (Hdim * NE)  // f16 elements per plane (1,048,576 = 2 MB)
#define CHUNK_ELEMS 8192         // f16 elements per K-chunk image (16 KB)

// Scales (exact powers of two; undone in epilogue):
//   W' = 64*w, X' = 16*x, m-planes additionally *2048.
//   logit = (acc0 + acc1*2^-11) * 2^-10   (mm product dropped: validated R6-R20)
#define C0 9.765625e-4f            // 2^-10
#define C1 4.76837158203125e-7f    // 2^-21

typedef _Float16 f16x8 __attribute__((ext_vector_type(8)));
typedef _Float16 f16x4 __attribute__((ext_vector_type(4)));
typedef float f32x4 __attribute__((ext_vector_type(4)));

// lgkm-only barrier: orders LDS ops; register-held global prefetch stays
// in flight across it (R13-R20 verified).
#define KBAR()                                               \
  {                                                          \
    asm volatile("s_waitcnt lgkmcnt(0)" ::: "memory");       \
    __builtin_amdgcn_s_barrier();                            \
  }

// ---------------------------------------------------------------------------
// W [256][4096] fp32 -> 2 f16 planes (h, m). Plane layout: [k8][n] chunks of
// 8 f16 (16 B) — per-lane fragment loads are coalesced.
// ---------------------------------------------------------------------------
__global__ __launch_bounds__(256)
void convert_w(const float* __restrict__ W, _Float16* __restrict__ pl) {
  const int id = blockIdx.x * 256 + threadIdx.x;  // 0 .. 131071
  const int k8 = id & 511;
  const int n = id >> 9;
  const float* src = W + (long)n * Hdim + k8 * 8;
  const float4 x0 = *(const float4*)src;
  const float4 x1 = *(const float4*)(src + 4);
  const float xv[8] = {x0.x, x0.y, x0.z, x0.w, x1.x, x1.y, x1.z, x1.w};
  f16x8 vh, vm;
#pragma unroll
  for (int j = 0; j < 8; ++j) {
    const float v = xv[j] * 64.f;
    const _Float16 h = (_Float16)v;
    const float r = (v - (float)h) * 2048.f;
    vh[j] = h;
    vm[j] = (_Float16)r;
  }
  const long co = ((long)k8 * NE + n) * 8;
  *(f16x8*)(pl + co) = vh;
  *(f16x8*)(pl + PLANE_ELEMS + co) = vm;
}

// ---------------------------------------------------------------------------
// Fused: logits = X @ W^T via 3-product split-f16 MFMA, then top-k epilogue.
// R20-verified quad structure coarsened to OCTO phases: 8 chunks per barrier
// (16 barriers, was 32). BM=64, grid=256 (1 block/CU), 512 thr = 8 waves,
// wave = 32 DISTINCT experts x all 64 tokens (W once-per-CU per chunk).
//   - X: depth-2 register pipeline (XA/XB, 8 float4 each). Octo o: load octo
//     o+2 into regs; WRITE octo o+1 into the LDS ring in TWO 4-chunk halves
//     mid-phase (after COMPUTE 2 and 5) -> ds_writes spread, off barrier path.
//   - W: chunk-level register dbuf (wA/wB), 1-chunk-ahead prefetch pinned
//     with sched_barrier (R14 mechanism).
// LDS: X octo-ring 2 x 64 KB = 128 KB @0; epilogue lg [64][260] f32 aliases.
// ---------------------------------------------------------------------------
__global__ __launch_bounds__(512, 2)
void moe_gate_fused(const float* __restrict__ X, const _Float16* __restrict__ pl,
                    const float* __restrict__ bias, float* __restrict__ out, int T) {
  __shared__ __align__(16) unsigned char smem[131072];
  const int tid = threadIdx.x;
  const int lane = tid & 63, wave = tid >> 6;      // wave = expert group (0..7)
  const int r16 = lane & 15, c4 = lane >> 4;
  const long bm0 = (long)blockIdx.x * BM;

  f32x4 acc0[4][2], acc1[4][2];
#pragma unroll
  for (int i = 0; i < 4; ++i)
#pragma unroll
    for (int j = 0; j < 2; ++j) {
      acc0[i][j] = (f32x4)(0.f);
      acc1[i][j] = (f32x4)(0.f);
    }

  // X staging geometry: 512 threads -> (token xm 0..63, f4-slot 0..7);
  // per octo each thread stages 8 float4 (one per chunk).
  const int xm = tid >> 3;
  const int f4 = tid & 7;
  const float* xsrc = X + (bm0 + xm) * (long)Hdim + f4 * 4;  // + octo*256 + c*32
  const int k8w = f4 >> 1, hw = f4 & 1;
  const int xws = k8w * 1024 + xm * 16 + hw * 8;  // within (chunk, plane) region

  // per-lane W-fragment sources: expert n = wave*32 + fn*16 + r16, k8 = c4
  const _Float16* wsrc0 = pl + ((size_t)(c4 * 256 + wave * 32 + r16)) * 8;
  const _Float16* wsrc1 = wsrc0 + PLANE_ELEMS;

  f16x8 wA[2][2], wB[2][2];        // [plane][fn] — one chunk each
  float4 XA[8], XB[8];             // depth-2 X octo pipeline

#define LOADW(dst, kc_)                                                         \
  {                                                                             \
    const size_t ko = (size_t)(kc_) * CHUNK_ELEMS;                              \
    _Pragma("unroll") for (int fn = 0; fn < 2; ++fn) {                          \
      dst[0][fn] = *(const f16x8*)(wsrc0 + ko + fn * 128);                      \
      dst[1][fn] = *(const f16x8*)(wsrc1 + ko + fn * 128);                      \
    }                                                                           \
  }

#define LOADX(dst, o_)                                                          \
  {                                                                             \
    _Pragma("unroll") for (int c = 0; c < 8; ++c)                               \
        dst[c] = *(const float4*)(xsrc + (size_t)(o_) * 256 + c * 32);          \
  }

// Write chunks [c0, c0+4) of octo buffer qb from src_ registers.
#define WRITEX_H(qb, src_, c0)                                                  \
  {                                                                             \
    _Pragma("unroll") for (int c = (c0); c < (c0) + 4; ++c) {                   \
      f16x4 vh, vm;                                                             \
      const float xa[4] = {src_[c].x, src_[c].y, src_[c].z, src_[c].w};         \
      _Pragma("unroll") for (int j = 0; j < 4; ++j) {                           \
        const float v = xa[j] * 16.f;                                           \
        const _Float16 h = (_Float16)v;                                         \
        const float r = (v - (float)h) * 2048.f;                                \
        vh[j] = h;                                                              \
        vm[j] = (_Float16)r;                                                    \
      }                                                                         \
      const int xo = (qb) * 65536 + c * 8192 + xws;                             \
      *(f16x4*)&smem[xo] = vh;                                                  \
      *(f16x4*)&smem[xo + 4096] = vm;                                           \
    }                                                                           \
  }

#define COMPUTE(qb, c, wreg)                                                    \
  {                                                                             \
    const int xo = (qb) * 65536 + (c) * 8192;                                   \
    f16x8 af[2][4];                                                             \
    _Pragma("unroll") for (int p = 0; p < 2; ++p)                               \
        _Pragma("unroll") for (int fm = 0; fm < 4; ++fm)                        \
            af[p][fm] = *(const f16x8*)&smem[xo + p * 4096 + c4 * 1024 +        \
                                             (fm * 16 + r16) * 16];             \
    _Pragma("unroll") for (int fm = 0; fm < 4; ++fm)                            \
        _Pragma("unroll") for (int fn = 0; fn < 2; ++fn) {                      \
      acc0[fm][fn] = __builtin_amdgcn_mfma_f32_16x16x32_f16(                    \
          af[0][fm], wreg[0][fn], acc0[fm][fn], 0, 0, 0);                       \
      f32x4 s = acc1[fm][fn];                                                   \
      s = __builtin_amdgcn_mfma_f32_16x16x32_f16(af[0][fm], wreg[1][fn], s, 0, 0, 0); \
      s = __builtin_amdgcn_mfma_f32_16x16x32_f16(af[1][fm], wreg[0][fn], s, 0, 0, 0); \
      acc1[fm][fn] = s;                                                         \
    }                                                                           \
  }

// One octo phase: compute buf qb (chunks 8o..8o+7); load octo o+2 into XNXT;
// write octo o+1 (XCUR) into buf qb^1 in two halves; W chunk-dbuf rolls.
#define OCTO(qb, XCUR, XNXT, o_)                                                \
  {                                                                             \
    const int on2 = ((o_) + 2 < 16) ? (o_) + 2 : 15;                            \
    LOADX(XNXT, on2);                                                           \
    LOADW(wB, 8 * (o_) + 1);                                                    \
    __builtin_amdgcn_sched_barrier(0);                                          \
    COMPUTE(qb, 0, wA);                                                         \
    LOADW(wA, 8 * (o_) + 2);                                                    \
    __builtin_amdgcn_sched_barrier(0);                                          \
    COMPUTE(qb, 1, wB);                                                         \
    LOADW(wB, 8 * (o_) + 3);                                                    \
    __builtin_amdgcn_sched_barrier(0);                                          \
    COMPUTE(qb, 2, wA);                                                         \
    if ((o_) + 1 < 16) WRITEX_H((qb) ^ 1, XCUR, 0);                             \
    LOADW(wA, 8 * (o_) + 4);                                                    \
    __builtin_amdgcn_sched_barrier(0);                                          \
    COMPUTE(qb, 3, wB);                                                         \
    LOADW(wB, 8 * (o_) + 5);                                                    \
    __builtin_amdgcn_sched_barrier(0);                                          \
    COMPUTE(qb, 4, wA);                                                         \
    LOADW(wA, 8 * (o_) + 6);                                                    \
    __builtin_amdgcn_sched_barrier(0);                                          \
    COMPUTE(qb, 5, wB);                                                         \
    if ((o_) + 1 < 16) WRITEX_H((qb) ^ 1, XCUR, 4);                             \
    LOADW(wB, 8 * (o_) + 7);                                                    \
    __builtin_amdgcn_sched_barrier(0);                                          \
    COMPUTE(qb, 6, wA);                                                         \
    {                                                                           \
      const int kcn = (8 * (o_) + 8 < NKC) ? 8 * (o_) + 8 : NKC - 1;            \
      LOADW(wA, kcn);                                                           \
    }                                                                           \
    __builtin_amdgcn_sched_barrier(0);                                          \
    COMPUTE(qb, 7, wB);                                                         \
    KBAR();                                                                     \
  }

  // prologue: octo 0 -> LDS buf0; octo 1 -> XA (written during octo 0);
  // W chunk 0 -> wA.
  LOADX(XA, 0);
  WRITEX_H(0, XA, 0);
  WRITEX_H(0, XA, 4);
  LOADX(XA, 1);
  LOADW(wA, 0);
  __syncthreads();

  for (int o = 0; o < 16; o += 2) {
    OCTO(0, XA, XB, o);      // compute buf0; stage octo o+1 (XA) -> buf1
    OCTO(1, XB, XA, o + 1);  // compute buf1; stage octo o+2 (XB) -> buf0
  }

  // ---- epilogue: logits -> LDS [64][260] fp32, then fused top-k ----
  __syncthreads();  // full drain before aliasing smem with lg
  float* lg = (float*)smem;
#pragma unroll
  for (int fm = 0; fm < 4; ++fm)
#pragma unroll
    for (int fn = 0; fn < 2; ++fn)
#pragma unroll
      for (int r = 0; r < 4; ++r) {
        const int t = fm * 16 + c4 * 4 + r;
        const int n = wave * 32 + fn * 16 + r16;
        lg[t * 260 + n] = fmaf(acc1[fm][fn][r], C1, acc0[fm][fn][r] * C0);
      }
  __syncthreads();

  // phase 2 (verified rounds 1-20 logic): wave processes 8 tokens sequentially
  const float4 bv = *(const float4*)(bias + lane * 4);
  for (int i = 0; i < 8; ++i) {
    const int t = wave * 8 + i;
    const float4 lgv = *(const float4*)&lg[t * 260 + lane * 4];

    const float s0 = 1.f / (1.f + expf(-lgv.x));
    const float s1 = 1.f / (1.f + expf(-lgv.y));
    const float s2 = 1.f / (1.f + expf(-lgv.z));
    const float s3 = 1.f / (1.f + expf(-lgv.w));

    const float c0 = s0 + bv.x, c1 = s1 + bv.y, c2 = s2 + bv.z, c3 = s3 + bv.w;

    // lane-local top2 of 4
    float m1 = fmaxf(c0, c1), m2 = fminf(c0, c1);
    if (c2 > m1) { m2 = m1; m1 = c2; } else m2 = fmaxf(m2, c2);
    if (c3 > m1) { m2 = m1; m1 = c3; } else m2 = fmaxf(m2, c3);
#pragma unroll
    for (int off = 1; off < 8; off <<= 1) {
      const float o1 = __shfl_xor(m1, off);
      const float o2 = __shfl_xor(m2, off);
      if (o1 > m1) { m2 = fmaxf(m1, o2); m1 = o1; }
      else m2 = fmaxf(m2, o1);
    }
    const float gs = m1 + m2;  // group score (identical across the 8 lanes)

    const int gme = lane >> 3;
    int rank = 0;
#pragma unroll
    for (int j = 0; j < 8; ++j) {
      const float gj = __shfl(gs, j * 8);
      rank += ((gj > gs) || (gj == gs && j < gme)) ? 1 : 0;
    }
    const bool sel = rank < 4;

    const float NEG = -INFINITY;
    float q0 = sel ? c0 : NEG, q1 = sel ? c1 : NEG;
    float q2 = sel ? c2 : NEG, q3 = sel ? c3 : NEG;

    float sum = 0.f;
    int my_e = 0;
    float my_w = 0.f;
#pragma unroll
    for (int r = 0; r < 8; ++r) {
      float v = q0; int ix = 0;
      if (q1 > v) { v = q1; ix = 1; }
      if (q2 > v) { v = q2; ix = 2; }
      if (q3 > v) { v = q3; ix = 3; }
      int e = lane * 4 + ix;
#pragma unroll
      for (int off = 1; off < 64; off <<= 1) {
        const float v2 = __shfl_xor(v, off);
        const int e2 = __shfl_xor(e, off);
        const bool take = (v2 > v) || (v2 == v && e2 < e);
        v = take ? v2 : v;
        e = take ? e2 : e;
      }
      const int slot = e & 3, owner = e >> 2;
      const float svs = (slot == 0) ? s0 : ((slot == 1) ? s1 : ((slot == 2) ? s2 : s3));
      const float wgt = __shfl(svs, owner);
      sum += wgt;
      if (lane == r) { my_e = e; my_w = wgt; }
      const bool own = (lane == owner);
      q0 = (own && slot == 0) ? NEG : q0;
      q1 = (own && slot == 1) ? NEG : q1;
      q2 = (own && slot == 2) ? NEG : q2;
      q3 = (own && slot == 3) ? NEG : q3;
    }

    if (lane < 8) {
      const float denom = sum + 1e-20f;
      const long tg = bm0 + t;
      out[tg * 8 + lane] = (float)my_e;
      out[(long)T * 8 + tg * 8 + lane] = my_w / denom * 2.5f;
    }
  }
}

// ---------------------------------------------------------------------------
extern "C" void kernel_launch(void* const* d_in, const int* in_sizes, int n_in,
                              void* d_out, int out_size, void* d_ws, size_t ws_size,
                              hipStream_t stream) {
  const float* X = (const float*)d_in[0];   // [T, 4096]
  const float* W = (const float*)d_in[1];   // [256, 4096]
  const float* B = (const float*)d_in[2];   // [256]
  float* out = (float*)d_out;
  const int T = in_sizes[0] / Hdim;         // 16384

  _Float16* planes = (_Float16*)d_ws;       // 2 x 2 MB = 4 MB scratch

  convert_w<<<512, 256, 0, stream>>>(W, planes);
  moe_gate_fused<<<T / BM, 512, 0, stream>>>(X, planes, B, out, T);
}

// Round 22
// 148.638 us; speedup vs baseline: 1.0123x; 1.0123x over previous
//
#include <hip/hip_runtime.h>
#include <math.h>

#define Hdim 4096
#define NE 256
#define BM 64
#define BK 32
#define NKC (Hdim / BK)          // 128 K-chunks = 32 quads
#define PLANE_ELEMS (Hdim * NE)  // f16 elements per plane (1,048,576 = 2 MB)
#define CHUNK_ELEMS 8192         // f16 elements per K-chunk image (16 KB)

// Scales (exact powers of two; undone in epilogue):
//   W' = 64*w, X' = 16*x, m-planes additionally *2048.
//   logit = (acc0 + acc1*2^-11) * 2^-10   (mm product dropped: validated R6-R21)
#define C0 9.765625e-4f            // 2^-10
#define C1 4.76837158203125e-7f    // 2^-21

typedef _Float16 f16x8 __attribute__((ext_vector_type(8)));
typedef _Float16 f16x4 __attribute__((ext_vector_type(4)));
typedef float f32x4 __attribute__((ext_vector_type(4)));

// lgkm-only barrier: orders LDS ops; register-held global prefetch stays
// in flight across it (R13-R21 verified).
#define KBAR()                                               \
  {                                                          \
    asm volatile("s_waitcnt lgkmcnt(0)" ::: "memory");       \
    __builtin_amdgcn_s_barrier();                            \
  }

// ---------------------------------------------------------------------------
// W [256][4096] fp32 -> 2 f16 planes (h, m). Plane layout: [k8][n] chunks of
// 8 f16 (16 B) — per-lane fragment loads are coalesced.
// ---------------------------------------------------------------------------
__global__ __launch_bounds__(256)
void convert_w(const float* __restrict__ W, _Float16* __restrict__ pl) {
  const int id = blockIdx.x * 256 + threadIdx.x;  // 0 .. 131071
  const int k8 = id & 511;
  const int n = id >> 9;
  const float* src = W + (long)n * Hdim + k8 * 8;
  const float4 x0 = *(const float4*)src;
  const float4 x1 = *(const float4*)(src + 4);
  const float xv[8] = {x0.x, x0.y, x0.z, x0.w, x1.x, x1.y, x1.z, x1.w};
  f16x8 vh, vm;
#pragma unroll
  for (int j = 0; j < 8; ++j) {
    const float v = xv[j] * 64.f;
    const _Float16 h = (_Float16)v;
    const float r = (v - (float)h) * 2048.f;
    vh[j] = h;
    vm[j] = (_Float16)r;
  }
  const long co = ((long)k8 * NE + n) * 8;
  *(f16x8*)(pl + co) = vh;
  *(f16x8*)(pl + PLANE_ELEMS + co) = vm;
}

// ---------------------------------------------------------------------------
// FINAL (R20 best-measured): logits = X @ W^T via 3-product split-f16 MFMA,
// fused top-k epilogue. BM=64, grid=256 (1 block/CU), 512 thr = 8 waves,
// wave = 32 DISTINCT experts x all 64 tokens (W fetched once per CU per
// chunk — the binding traffic optimum). QUAD phases: 4 chunks per barrier.
//   - X: depth-2 register pipeline (XA/XB); quad q+1 written to the LDS ring
//     mid-quad, fully off the barrier critical path.
//   - W: chunk-level register dbuf (wA/wB), 1-chunk-ahead prefetch pinned
//     with sched_barrier.
// LDS: X quad-ring 2 x 32 KB @0; epilogue lg [64][260] f32 (66.5 KB).
// ---------------------------------------------------------------------------
__global__ __launch_bounds__(512, 2)
void moe_gate_fused(const float* __restrict__ X, const _Float16* __restrict__ pl,
                    const float* __restrict__ bias, float* __restrict__ out, int T) {
  __shared__ __align__(16) unsigned char smem[66560];
  const int tid = threadIdx.x;
  const int lane = tid & 63, wave = tid >> 6;      // wave = expert group (0..7)
  const int r16 = lane & 15, c4 = lane >> 4;
  const long bm0 = (long)blockIdx.x * BM;

  f32x4 acc0[4][2], acc1[4][2];
#pragma unroll
  for (int i = 0; i < 4; ++i)
#pragma unroll
    for (int j = 0; j < 2; ++j) {
      acc0[i][j] = (f32x4)(0.f);
      acc1[i][j] = (f32x4)(0.f);
    }

  // X staging geometry: 512 threads -> (token xm 0..63, f4-slot 0..7);
  // per quad each thread stages 4 float4 (one per chunk).
  const int xm = tid >> 3;
  const int f4 = tid & 7;
  const float* xsrc = X + (bm0 + xm) * (long)Hdim + f4 * 4;  // + quad*128 + c*32
  const int k8w = f4 >> 1, hw = f4 & 1;
  const int xws = k8w * 1024 + xm * 16 + hw * 8;  // within (chunk, plane) region

  // per-lane W-fragment sources: expert n = wave*32 + fn*16 + r16, k8 = c4
  const _Float16* wsrc0 = pl + ((size_t)(c4 * 256 + wave * 32 + r16)) * 8;
  const _Float16* wsrc1 = wsrc0 + PLANE_ELEMS;

  f16x8 wA[2][2], wB[2][2];        // [plane][fn] — one chunk each
  float4 XA[4], XB[4];             // depth-2 X quad pipeline

#define LOADW(dst, kc_)                                                         \
  {                                                                             \
    const size_t ko = (size_t)(kc_) * CHUNK_ELEMS;                              \
    _Pragma("unroll") for (int fn = 0; fn < 2; ++fn) {                          \
      dst[0][fn] = *(const f16x8*)(wsrc0 + ko + fn * 128);                      \
      dst[1][fn] = *(const f16x8*)(wsrc1 + ko + fn * 128);                      \
    }                                                                           \
  }

#define LOADX(dst, q_)                                                          \
  {                                                                             \
    _Pragma("unroll") for (int c = 0; c < 4; ++c)                               \
        dst[c] = *(const float4*)(xsrc + (size_t)(q_) * 128 + c * 32);          \
  }

#define WRITEX(qb, src_)                                                        \
  {                                                                             \
    _Pragma("unroll") for (int c = 0; c < 4; ++c) {                             \
      f16x4 vh, vm;                                                             \
      const float xa[4] = {src_[c].x, src_[c].y, src_[c].z, src_[c].w};         \
      _Pragma("unroll") for (int j = 0; j < 4; ++j) {                           \
        const float v = xa[j] * 16.f;                                           \
        const _Float16 h = (_Float16)v;                                         \
        const float r = (v - (float)h) * 2048.f;                                \
        vh[j] = h;                                                              \
        vm[j] = (_Float16)r;                                                    \
      }                                                                         \
      const int xo = (qb) * 32768 + c * 8192 + xws;                             \
      *(f16x4*)&smem[xo] = vh;                                                  \
      *(f16x4*)&smem[xo + 4096] = vm;                                           \
    }                                                                           \
  }

#define COMPUTE(qb, c, wreg)                                                    \
  {                                                                             \
    const int xo = (qb) * 32768 + (c) * 8192;                                   \
    f16x8 af[2][4];                                                             \
    _Pragma("unroll") for (int p = 0; p < 2; ++p)                               \
        _Pragma("unroll") for (int fm = 0; fm < 4; ++fm)                        \
            af[p][fm] = *(const f16x8*)&smem[xo + p * 4096 + c4 * 1024 +        \
                                             (fm * 16 + r16) * 16];             \
    _Pragma("unroll") for (int fm = 0; fm < 4; ++fm)                            \
        _Pragma("unroll") for (int fn = 0; fn < 2; ++fn) {                      \
      acc0[fm][fn] = __builtin_amdgcn_mfma_f32_16x16x32_f16(                    \
          af[0][fm], wreg[0][fn], acc0[fm][fn], 0, 0, 0);                       \
      f32x4 s = acc1[fm][fn];                                                   \
      s = __builtin_amdgcn_mfma_f32_16x16x32_f16(af[0][fm], wreg[1][fn], s, 0, 0, 0); \
      s = __builtin_amdgcn_mfma_f32_16x16x32_f16(af[1][fm], wreg[0][fn], s, 0, 0, 0); \
      acc1[fm][fn] = s;                                                         \
    }                                                                           \
  }

// One quad phase: compute buf qb (chunks 4q..4q+3); load quad q+2 into XNXT;
// write quad q+1 (XCUR) into buf qb^1 mid-quad; W chunk-dbuf rolls forward.
#define QUAD(qb, XCUR, XNXT, q_)                                                \
  {                                                                             \
    const int qn2 = ((q_) + 2 < 32) ? (q_) + 2 : 31;                            \
    LOADX(XNXT, qn2);                                                           \
    LOADW(wB, 4 * (q_) + 1);                                                    \
    __builtin_amdgcn_sched_barrier(0);                                          \
    COMPUTE(qb, 0, wA);                                                         \
    LOADW(wA, 4 * (q_) + 2);                                                    \
    __builtin_amdgcn_sched_barrier(0);                                          \
    COMPUTE(qb, 1, wB);                                                         \
    if ((q_) + 1 < 32) WRITEX((qb) ^ 1, XCUR);                                  \
    LOADW(wB, 4 * (q_) + 3);                                                    \
    __builtin_amdgcn_sched_barrier(0);                                          \
    COMPUTE(qb, 2, wA);                                                         \
    {                                                                           \
      const int kcn = (4 * (q_) + 4 < NKC) ? 4 * (q_) + 4 : NKC - 1;            \
      LOADW(wA, kcn);                                                           \
    }                                                                           \
    __builtin_amdgcn_sched_barrier(0);                                          \
    COMPUTE(qb, 3, wB);                                                         \
    KBAR();                                                                     \
  }

  // prologue: quad 0 -> LDS buf0; quad 1 -> XA (written during quad 0);
  // W chunk 0 -> wA.
  LOADX(XA, 0);
  WRITEX(0, XA);
  LOADX(XA, 1);
  LOADW(wA, 0);
  __syncthreads();

  for (int q = 0; q < 32; q += 2) {
    QUAD(0, XA, XB, q);      // compute buf0; stage quad q+1 (XA) -> buf1
    QUAD(1, XB, XA, q + 1);  // compute buf1; stage quad q+2 (XB) -> buf0
  }

  // ---- epilogue: logits -> LDS [64][260] fp32, then fused top-k ----
  __syncthreads();  // full drain before aliasing smem with lg
  float* lg = (float*)smem;
#pragma unroll
  for (int fm = 0; fm < 4; ++fm)
#pragma unroll
    for (int fn = 0; fn < 2; ++fn)
#pragma unroll
      for (int r = 0; r < 4; ++r) {
        const int t = fm * 16 + c4 * 4 + r;
        const int n = wave * 32 + fn * 16 + r16;
        lg[t * 260 + n] = fmaf(acc1[fm][fn][r], C1, acc0[fm][fn][r] * C0);
      }
  __syncthreads();

  // phase 2 (verified rounds 1-21 logic): wave processes 8 tokens sequentially
  const float4 bv = *(const float4*)(bias + lane * 4);
  for (int i = 0; i < 8; ++i) {
    const int t = wave * 8 + i;
    const float4 lgv = *(const float4*)&lg[t * 260 + lane * 4];

    const float s0 = 1.f / (1.f + expf(-lgv.x));
    const float s1 = 1.f / (1.f + expf(-lgv.y));
    const float s2 = 1.f / (1.f + expf(-lgv.z));
    const float s3 = 1.f / (1.f + expf(-lgv.w));

    const float c0 = s0 + bv.x, c1 = s1 + bv.y, c2 = s2 + bv.z, c3 = s3 + bv.w;

    // lane-local top2 of 4
    float m1 = fmaxf(c0, c1), m2 = fminf(c0, c1);
    if (c2 > m1) { m2 = m1; m1 = c2; } else m2 = fmaxf(m2, c2);
    if (c3 > m1) { m2 = m1; m1 = c3; } else m2 = fmaxf(m2, c3);
#pragma unroll
    for (int off = 1; off < 8; off <<= 1) {
      const float o1 = __shfl_xor(m1, off);
      const float o2 = __shfl_xor(m2, off);
      if (o1 > m1) { m2 = fmaxf(m1, o2); m1 = o1; }
      else m2 = fmaxf(m2, o1);
    }
    const float gs = m1 + m2;  // group score (identical across the 8 lanes)

    const int gme = lane >> 3;
    int rank = 0;
#pragma unroll
    for (int j = 0; j < 8; ++j) {
      const float gj = __shfl(gs, j * 8);
      rank += ((gj > gs) || (gj == gs && j < gme)) ? 1 : 0;
    }
    const bool sel = rank < 4;

    const float NEG = -INFINITY;
    float q0 = sel ? c0 : NEG, q1 = sel ? c1 : NEG;
    float q2 = sel ? c2 : NEG, q3 = sel ? c3 : NEG;

    float sum = 0.f;
    int my_e = 0;
    float my_w = 0.f;
#pragma unroll
    for (int r = 0; r < 8; ++r) {
      float v = q0; int ix = 0;
      if (q1 > v) { v = q1; ix = 1; }
      if (q2 > v) { v = q2; ix = 2; }
      if (q3 > v) { v = q3; ix = 3; }
      int e = lane * 4 + ix;
#pragma unroll
      for (int off = 1; off < 64; off <<= 1) {
        const float v2 = __shfl_xor(v, off);
        const int e2 = __shfl_xor(e, off);
        const bool take = (v2 > v) || (v2 == v && e2 < e);
        v = take ? v2 : v;
        e = take ? e2 : e;
      }
      const int slot = e & 3, owner = e >> 2;
      const float svs = (slot == 0) ? s0 : ((slot == 1) ? s1 : ((slot == 2) ? s2 : s3));
      const float wgt = __shfl(svs, owner);
      sum += wgt;
      if (lane == r) { my_e = e; my_w = wgt; }
      const bool own = (lane == owner);
      q0 = (own && slot == 0) ? NEG : q0;
      q1 = (own && slot == 1) ? NEG : q1;
      q2 = (own && slot == 2) ? NEG : q2;
      q3 = (own && slot == 3) ? NEG : q3;
    }

    if (lane < 8) {
      const float denom = sum + 1e-20f;
      const long tg = bm0 + t;
      out[tg * 8 + lane] = (float)my_e;
      out[(long)T * 8 + tg * 8 + lane] = my_w / denom * 2.5f;
    }
  }
}

// ---------------------------------------------------------------------------
extern "C" void kernel_launch(void* const* d_in, const int* in_sizes, int n_in,
                              void* d_out, int out_size, void* d_ws, size_t ws_size,
                              hipStream_t stream) {
  const float* X = (const float*)d_in[0];   // [T, 4096]
  const float* W = (const float*)d_in[1];   // [256, 4096]
  const float* B = (const float*)d_in[2];   // [256]
  float* out = (float*)d_out;
  const int T = in_sizes[0] / Hdim;         // 16384

  _Float16* planes = (_Float16*)d_ws;       // 2 x 2 MB = 4 MB scratch

  convert_w<<<512, 256, 0, stream>>>(W, planes);
  moe_gate_fused<<<T / BM, 512, 0, stream>>>(X, planes, B, out, T);
}